// Round 9
// baseline (4420.995 us; speedup 1.0000x reference)
//
#include <hip/hip_runtime.h>

// Echo-state RNN, B=32, T=2048, NH=512.  W_hh ~90% exact zeros.
// r8 post-mortem: every config lands at ~6 cyc per divergent wave-gather per
// CU (= m134's single-wave ds_read_b32 throughput) -- the CU LDS unit is the
// wall. NEW: split each batch across SQ=4 CUs (128 blocks x 128 threads);
// per-CU gathers drop ~3.4x. Per-step all-to-all of the 512 t-values among a
// batch's 4 blocks via SELF-TAGGED 8-byte relaxed agent atomics
// ((tag<<32)|f32): readers poll for exact tag -- no flags, no fences, no L2
// writeback, no vmcnt drain; the 8B atomicity carries the ordering. Two
// alternating buffers; a block overwrites exchange #s only after reading
// #(s+1) from all peers (safe by induction). Stale tags across graph replays
// either mismatch or carry bit-identical deterministic values. z goes as 4
// tagged quarter-partials summed in fixed order. All 128 blocks co-resident.

#define NH   512
#define TT   2048
#define BB   32
#define SQ   4
#define TPB  128
#define PAD  96
#define PIN  96

typedef unsigned long long u64;

// ---------------------------------------------------------------------------
// A: nnz per row (wave-per-row ballot count)
// ---------------------------------------------------------------------------
__global__ __launch_bounds__(512) void count_nnz(
    const float* __restrict__ Whh, int* __restrict__ nnz) {
  const int wib  = threadIdx.x >> 6;
  const int lane = threadIdx.x & 63;
  const int row  = blockIdx.x * 8 + wib;
  const float* wrow = Whh + (size_t)row * NH;
  int cnt = 0;
  for (int c = 0; c < NH / 64; ++c)
    cnt += __popcll(__ballot(wrow[c * 64 + lane] != 0.0f));
  if (lane == 0) nnz[row] = cnt;
}

// ---------------------------------------------------------------------------
// B: rank rows by nnz descending (stable). perm[p] = row at sorted pos p.
// ---------------------------------------------------------------------------
__global__ __launch_bounds__(512) void sort_rows(
    const int* __restrict__ nnz, int* __restrict__ perm) {
  __shared__ int nl[NH];
  const int j = threadIdx.x;
  const int my = nnz[j];
  nl[j] = my;
  __syncthreads();
  int r = 0;
  const int4* p4 = (const int4*)nl;
  for (int i = 0; i < NH / 4; ++i) {
    int4 v = p4[i];
    const int base = i * 4;
    r += (v.x > my) || (v.x == my && base + 0 < j);
    r += (v.y > my) || (v.y == my && base + 1 < j);
    r += (v.z > my) || (v.z == my && base + 2 < j);
    r += (v.w > my) || (v.w == my && base + 3 < j);
  }
  perm[r] = j;
}

// ---------------------------------------------------------------------------
// C: gather schedule, one WAVE per block (grid=8), soft cap 2 per
// (half-wave, bank). Same as round 8.
// ---------------------------------------------------------------------------
__global__ __launch_bounds__(64) void build_schedule(
    const float* __restrict__ Whh, const int* __restrict__ perm,
    float* __restrict__ vals, unsigned* __restrict__ offs,
    int* __restrict__ cntw) {
  __shared__ int cnt[2][32];
  const int lane = threadIdx.x;
  const int wid  = blockIdx.x;
  const int p    = wid * 64 + lane;
  const int half = lane >> 5;
  const int home = lane & 31;
  const int row  = perm[p];
  const float* wrow = Whh + (size_t)row * NH;

  unsigned occ32[16];
  int remaining = 0;
  unsigned nonempty = 0;
  #pragma unroll
  for (int r = 0; r < 16; ++r) {
    unsigned lo = 0, hi = 0;
    #pragma unroll
    for (int m = 0; m < 16; ++m) {
      lo |= (wrow[(2 * r)     + 32 * m] != 0.f) ? (1u << m) : 0u;
      hi |= (wrow[(2 * r + 1) + 32 * m] != 0.f) ? (1u << m) : 0u;
    }
    occ32[r] = lo | (hi << 16);
    remaining += __popc(lo) + __popc(hi);
    if (lo) nonempty |= 1u << (2 * r);
    if (hi) nonempty |= 1u << (2 * r + 1);
  }

  int s = 0;
  while (__ballot(remaining > 0) != 0ull && s < PAD) {
    cnt[half][home] = 0;
    __builtin_amdgcn_wave_barrier();

    bool placed = false;
    int  mybank = 0;
    unsigned excl = 0;

    for (int round = 0; round < 10; ++round) {
      const int cap = (round < 3) ? 1 : 2;
      if (round == 3) excl = 0;
      unsigned cand = (placed || remaining == 0) ? 0u : (nonempty & ~excl);
      bool want = cand != 0u;
      int bl = 0;
      if (want) {
        unsigned rot = home ? ((cand >> home) | (cand << (32 - home))) : cand;
        bl = (home + __ffs(rot) - 1) & 31;
      }
      if (__ballot(want) == 0ull) break;
      if (want) {
        int old = atomicAdd(&cnt[half][bl], 1);
        if (old < cap) { placed = true; mybank = bl; }
        else { atomicSub(&cnt[half][bl], 1); excl |= 1u << bl; }
      }
      __builtin_amdgcn_wave_barrier();
    }

    if (!placed && remaining > 0 && (PAD - s) <= remaining) {
      placed = true;
      mybank = __ffs(nonempty) - 1;
    }

    float v = 0.f; unsigned col = 0u;
    if (placed) {
      #pragma unroll
      for (int r = 0; r < 16; ++r) {
        if (r == (mybank >> 1)) {
          unsigned w   = occ32[r];
          unsigned m16 = (mybank & 1) ? (w >> 16) : (w & 0xFFFFu);
          int m = __ffs(m16) - 1;
          col = (unsigned)(mybank + 32 * m);
          unsigned nm = m16 & (m16 - 1u);
          occ32[r] = (mybank & 1) ? ((w & 0x0000FFFFu) | (nm << 16))
                                  : ((w & 0xFFFF0000u) | nm);
          if (nm == 0u) nonempty &= ~(1u << mybank);
        }
      }
      v = wrow[col];
      --remaining;
    }
    vals[s * NH + p] = v;
    offs[s * NH + p] = col;
    ++s;
  }
  if (lane == 0) cntw[wid] = s;
  for (int e = s; e < PAD; ++e) {
    vals[e * NH + p] = 0.f;
    offs[e * NH + p] = 0u;
  }
}

// ---------------------------------------------------------------------------
// DPP wave-64 sum reduction (VALU pipe); lane 63 ends with the full sum.
// ---------------------------------------------------------------------------
template <int CTRL, int RM>
__device__ __forceinline__ float dppadd(float v) {
  int t = __builtin_amdgcn_update_dpp(0, __float_as_int(v), CTRL, RM, 0xF, true);
  return v + __int_as_float(t);
}
__device__ __forceinline__ float wave_sum_lane63(float v) {
  v = dppadd<0xB1,  0xF>(v);
  v = dppadd<0x4E,  0xF>(v);
  v = dppadd<0x141, 0xF>(v);
  v = dppadd<0x140, 0xF>(v);
  v = dppadd<0x142, 0xA>(v);
  v = dppadd<0x143, 0xC>(v);
  return v;
}

__device__ __forceinline__ float ftanh(float x) {
  float xc = fminf(9.0f, fmaxf(-9.0f, x));
  float t  = __expf(2.0f * xc);
  return (t - 1.0f) * __builtin_amdgcn_rcpf(t + 1.0f);
}

__device__ __forceinline__ u64 aload(u64* p) {
  return __hip_atomic_load(p, __ATOMIC_RELAXED, __HIP_MEMORY_SCOPE_AGENT);
}
__device__ __forceinline__ void astore(u64* p, u64 v) {
  __hip_atomic_store(p, v, __ATOMIC_RELAXED, __HIP_MEMORY_SCOPE_AGENT);
}

#define GA(T_RD, E) (*(const float*)((const char*)(T_RD) + cidx[E]))

// barrier1 (red ready, gathers done) -> zq publish -> tagged poll -> tl
// refresh -> z combine/broadcast -> barrier2. lgkm-only barriers: no VMEM
// ordering needed (tags self-validate each 8B value).
#define EXCHANGE(TB, ZQ, TAG, DO_OZ, SIDX)                                   \
  {                                                                          \
    asm volatile("s_waitcnt lgkmcnt(0)\n\ts_barrier" ::: "memory");          \
    if (t == 0)                                                              \
      astore((ZQ) + q, ((u64)(TAG) << 32) |                                  \
                       (u64)__float_as_uint(red[0] + red[1]));               \
    u64 v0=0, v1=0, v2=0, v3=0, vz=0;                                        \
    bool o0=false, o1=false, o2=false, o3=false, ok_z = (t >= 4);            \
    for (;;) {                                                               \
      if (!o0)   v0 = aload((TB) + t);                                       \
      if (!o1)   v1 = aload((TB) + t + 128);                                 \
      if (!o2)   v2 = aload((TB) + t + 256);                                 \
      if (!o3)   v3 = aload((TB) + t + 384);                                 \
      if (!ok_z) vz = aload((ZQ) + t);                                       \
      o0 = (unsigned)(v0 >> 32) == (TAG);                                    \
      o1 = (unsigned)(v1 >> 32) == (TAG);                                    \
      o2 = (unsigned)(v2 >> 32) == (TAG);                                    \
      o3 = (unsigned)(v3 >> 32) == (TAG);                                    \
      ok_z = ok_z || ((unsigned)(vz >> 32) == (TAG));                        \
      if (o0 & o1 & o2 & o3 & ok_z) break;                                   \
    }                                                                        \
    tl[t]       = __uint_as_float((unsigned)v0);                             \
    tl[t + 128] = __uint_as_float((unsigned)v1);                             \
    tl[t + 256] = __uint_as_float((unsigned)v2);                             \
    tl[t + 384] = __uint_as_float((unsigned)v3);                             \
    if (w == 0) {                                                            \
      float zv = (t < 4) ? __uint_as_float((unsigned)vz) : 0.0f;             \
      float zz = (__shfl(zv, 0) + __shfl(zv, 1)) +                           \
                 (__shfl(zv, 2) + __shfl(zv, 3));                            \
      if (t == 0) { zbc = zz; if ((DO_OZ) && q == 0) oz[SIDX] = zz; }        \
    }                                                                        \
    asm volatile("s_waitcnt lgkmcnt(0)\n\ts_barrier" ::: "memory");          \
    z_prev = zbc;                                                            \
  }

// ---------------------------------------------------------------------------
// Main: 128 blocks (batch b x quarter q) of 128 threads (2 waves).
// Block (b,q) owns sorted waves {q, 7-q} (snake pairing for balance).
// ---------------------------------------------------------------------------
__global__ __launch_bounds__(TPB, 1) void esn_split(
    const float* __restrict__ x,   const float* __restrict__ h0,
    const float* __restrict__ Wih, const float* __restrict__ Whz,
    const float* __restrict__ Wzh, const float* __restrict__ vals,
    const unsigned* __restrict__ offs, const int* __restrict__ perm,
    const int* __restrict__ cntw, u64* __restrict__ tbuf,
    u64* __restrict__ zq, float* __restrict__ out) {
  __shared__ float tl[NH];                    // full t vector (local copy)
  __shared__ float x_lds[TT];
  __shared__ float red[2];                    // per-wave z partials
  __shared__ float zbc;                       // broadcast z

  const int t    = threadIdx.x;
  const int w    = t >> 6;
  const int lane = t & 63;
  // group a batch's 4 quarters onto one (empirical) XCD slot-set
  const int bid = blockIdx.x;
  const int xcd = bid & 7, sl = bid >> 3;
  const int b   = xcd * 4 + (sl >> 2);
  const int q   = sl & 3;
  const int g   = (w == 0) ? q : (7 - q);     // sorted wave-group owned
  const int p   = g * 64 + lane;              // sorted position
  const int row = perm[p];

  for (int i = t; i < TT; i += TPB) x_lds[i] = x[(size_t)b * TT + i];

  int cw = __builtin_amdgcn_readfirstlane((cntw[g] + 3) & ~3);

  float    wval[PAD];
  unsigned cidx[PAD];
  #pragma unroll
  for (int e = 0; e < PAD; ++e) {
    wval[e] = vals[e * NH + p];
    cidx[e] = offs[e * NH + p] * 4u;
  }
  #pragma unroll
  for (int e = 0; e < PIN; ++e)
    asm volatile("" : "+v"(wval[e]), "+v"(cidx[e]));

  const float w_ih = Wih[row];
  const float w_hz = Whz[row];
  const float w_zh = Wzh[row];
  float h = h0[(size_t)b * NH + row];
  float z_prev;

  float* oz = out + (size_t)b * TT;
  float* oh = out + (size_t)BB * TT + (size_t)b * TT * NH;

  // ---- prologue: exchange #0 = tanh(h0), tag 1 ----
  {
    float thn = ftanh(h);
    u64* tb  = tbuf + (size_t)b * NH;
    u64* zqb = zq   + (size_t)b * SQ;
    astore(tb + row, ((u64)1u << 32) | (u64)__float_as_uint(thn));
    float pzs = wave_sum_lane63(thn * w_hz);
    if (lane == 63) red[w] = pzs;
    EXCHANGE(tb, zqb, 1u, false, 0)
  }

  // ---- 2048 sequential steps ----
  for (int s = 0; s < TT; ++s) {
    float d0 = 0.f, d1 = 0.f, d2 = 0.f, d3 = 0.f;
    #pragma unroll
    for (int e = 0; e < PAD; e += 4) {
      if (e < cw) {
        d0 = fmaf(wval[e + 0], GA(tl, e + 0), d0);
        d1 = fmaf(wval[e + 1], GA(tl, e + 1), d1);
        d2 = fmaf(wval[e + 2], GA(tl, e + 2), d2);
        d3 = fmaf(wval[e + 3], GA(tl, e + 3), d3);
      }
    }
    float dot  = (d0 + d1) + (d2 + d3);

    float xp   = x_lds[s] * w_ih;
    float dhdt = ((dot - h) + xp) + z_prev * w_zh;
    float hn   = h + 0.1f * dhdt;             // alpha = dt/tau = 0.1
    __builtin_nontemporal_store(hn, &oh[(size_t)s * NH + row]);
    float thn  = ftanh(hn);

    const unsigned tg = (unsigned)(s + 2);
    const int buf = (s + 1) & 1;
    u64* tb  = tbuf + ((size_t)buf * BB + b) * NH;
    u64* zqb = zq   + ((size_t)buf * BB + b) * SQ;
    astore(tb + row, ((u64)tg << 32) | (u64)__float_as_uint(thn));
    float pzs = wave_sum_lane63(thn * w_hz);
    if (lane == 63) red[w] = pzs;

    EXCHANGE(tb, zqb, tg, true, s)
    h = hn;
  }
}

// ---------------------------------------------------------------------------
extern "C" void kernel_launch(void* const* d_in, const int* in_sizes, int n_in,
                              void* d_out, int out_size, void* d_ws,
                              size_t ws_size, hipStream_t stream) {
  const float* x   = (const float*)d_in[0];
  const float* h0  = (const float*)d_in[1];
  const float* Wih = (const float*)d_in[2];
  const float* Whh = (const float*)d_in[3];
  const float* Whz = (const float*)d_in[4];
  const float* Wzh = (const float*)d_in[5];
  float* out = (float*)d_out;

  char* ws = (char*)d_ws;
  float*    vals = (float*)ws;                           // 96*512*4 = 192 KB
  unsigned* offs = (unsigned*)(ws + 196608);             // 192 KB
  int*      nnz  = (int*)(ws + 393216);                  // 2 KB
  int*      perm = (int*)(ws + 395264);                  // 2 KB
  int*      cntw = (int*)(ws + 397312);                  // 64 B
  u64*      tbuf = (u64*)(ws + 397376);                  // 2*32*512*8 = 256 KB
  u64*      zqb  = (u64*)(ws + 659520);                  // 2*32*4*8 = 2 KB

  hipLaunchKernelGGL(count_nnz, dim3(NH / 8), dim3(512), 0, stream, Whh, nnz);
  hipLaunchKernelGGL(sort_rows, dim3(1), dim3(512), 0, stream, nnz, perm);
  hipLaunchKernelGGL(build_schedule, dim3(8), dim3(64), 0, stream,
                     Whh, perm, vals, offs, cntw);
  hipLaunchKernelGGL(esn_split, dim3(BB * SQ), dim3(TPB), 0, stream,
                     x, h0, Wih, Whz, Wzh, vals, offs, perm, cntw,
                     tbuf, zqb, out);
}

// Round 10
// 3195.967 us; speedup vs baseline: 1.3833x; 1.3833x over previous
//
#include <hip/hip_runtime.h>

// Echo-state RNN, B=32, T=2048, NH=512.  W_hh ~90% exact zeros.
// One workgroup (CU) per batch (r9's multi-CU split died on non-coherent-L2
// atomic polling: FETCH 204 MB/dispatch). Thread p owns row perm[p], rows
// sorted by nnz desc. Gather slots come from a PROPER KOENIG EDGE COLORING
// of each (wave, half-wave)'s lanes x banks multigraph: Delta colors =
// max(lane-deg, half-bank-deg) ~= 45..78 per wave (vs r7's greedy 96), and
// a proper coloring is <=1 access per (half,bank) per slot = zero conflicts.
// Coloring runs once (2 worker threads per wave-block, augmenting paths);
// a lane-parallel repair pass guarantees schedule VALIDITY regardless.
// esn_steps is round-7's kernel verbatim (best measured: 2406 us).

#define NH   512
#define TT   2048
#define BB   32
#define PAD  96
#define PIN  80
#define NONE_ 0xFF

// ---------------------------------------------------------------------------
// A: nnz per row (wave-per-row ballot count)
// ---------------------------------------------------------------------------
__global__ __launch_bounds__(512) void count_nnz(
    const float* __restrict__ Whh, int* __restrict__ nnz) {
  const int wib  = threadIdx.x >> 6;
  const int lane = threadIdx.x & 63;
  const int row  = blockIdx.x * 8 + wib;
  const float* wrow = Whh + (size_t)row * NH;
  int cnt = 0;
  for (int c = 0; c < NH / 64; ++c)
    cnt += __popcll(__ballot(wrow[c * 64 + lane] != 0.0f));
  if (lane == 0) nnz[row] = cnt;
}

// ---------------------------------------------------------------------------
// B: rank rows by nnz descending (stable). perm[p] = row at sorted pos p.
// ---------------------------------------------------------------------------
__global__ __launch_bounds__(512) void sort_rows(
    const int* __restrict__ nnz, int* __restrict__ perm) {
  __shared__ int nl[NH];
  const int j = threadIdx.x;
  const int my = nnz[j];
  nl[j] = my;
  __syncthreads();
  int r = 0;
  const int4* p4 = (const int4*)nl;
  for (int i = 0; i < NH / 4; ++i) {
    int4 v = p4[i];
    const int base = i * 4;
    r += (v.x > my) || (v.x == my && base + 0 < j);
    r += (v.y > my) || (v.y == my && base + 1 < j);
    r += (v.z > my) || (v.z == my && base + 2 < j);
    r += (v.w > my) || (v.w == my && base + 3 < j);
  }
  perm[r] = j;
}

// ---------------------------------------------------------------------------
// C: Koenig edge coloring per (wave, half). Block = wave g (grid 8, 64 thr).
// Threads 0 and 32 are the two half-workers; all 64 threads do load/repair/
// write. Edge (lane, bank) with multiplicity = nonzeros of that lane's row
// in that bank. Proper coloring: each lane's entries in distinct slots
// (validity) AND each (half,bank) <=1 per slot (zero LDS conflicts).
// ---------------------------------------------------------------------------
__global__ __launch_bounds__(64) void build_color(
    const float* __restrict__ Whh, const int* __restrict__ perm,
    float* __restrict__ vals, unsigned* __restrict__ offs,
    int* __restrict__ cntw) {
  __shared__ unsigned short occ[64][32];     // per-lane per-bank presence bits
  __shared__ unsigned char  mL[2][32][PAD];  // lane-side match: bank or NONE_
  __shared__ unsigned char  mB[2][32][PAD];  // bank-side match: lane or NONE_
  __shared__ unsigned freeL[2][32][3];       // 96-bit free-color masks
  __shared__ unsigned freeB[2][32][3];
  __shared__ short pB[2][128], pL[2][128];   // augmenting-path scratch
  __shared__ int cwsh;

  const int lane = threadIdx.x;
  const int g    = blockIdx.x;
  const int p    = g * 64 + lane;
  const int hl   = lane >> 5;
  const int li   = lane & 31;
  const int row  = perm[p];
  const float* wrow = Whh + (size_t)row * NH;

  if (lane == 0) cwsh = 0;
  for (int b = 0; b < 32; ++b) {
    unsigned m16 = 0;
    for (int m = 0; m < 16; ++m)
      m16 |= (wrow[b + 32 * m] != 0.f) ? (1u << m) : 0u;
    occ[lane][b] = (unsigned short)m16;
  }
  for (int c = 0; c < PAD; ++c) { mL[hl][li][c] = NONE_; mB[hl][li][c] = NONE_; }
  #pragma unroll
  for (int w2 = 0; w2 < 3; ++w2) {
    freeL[hl][li][w2] = 0xFFFFFFFFu;
    freeB[hl][li][w2] = 0xFFFFFFFFu;
  }
  __syncthreads();

  if (li == 0) {                             // workers: lanes 0 and 32
    int maxc = 0;
    for (int l = 0; l < 32; ++l) {           // ascending = degree-descending
      const int gl = hl * 32 + l;
      for (int b = 0; b < 32; ++b) {
        const int mult = __popc((unsigned)occ[gl][b]);
        for (int m = 0; m < mult; ++m) {
          // lowest color free at both endpoints
          int c = -1;
          #pragma unroll
          for (int w2 = 0; w2 < 3; ++w2) {
            unsigned cm = freeL[hl][l][w2] & freeB[hl][b][w2];
            if (cm) { c = w2 * 32 + __ffs(cm) - 1; break; }
          }
          if (c >= 0) {
            mL[hl][l][c] = (unsigned char)b;
            mB[hl][b][c] = (unsigned char)l;
            freeL[hl][l][c >> 5] &= ~(1u << (c & 31));
            freeB[hl][b][c >> 5] &= ~(1u << (c & 31));
            if (c > maxc) maxc = c;
            continue;
          }
          // augment: a = lowest free at lane, be = lowest free at bank
          int a = -1, be = -1;
          #pragma unroll
          for (int w2 = 0; w2 < 3; ++w2) {
            unsigned mm = freeL[hl][l][w2];
            if (mm) { a = w2 * 32 + __ffs(mm) - 1; break; }
          }
          #pragma unroll
          for (int w2 = 0; w2 < 3; ++w2) {
            unsigned mm = freeB[hl][b][w2];
            if (mm) { be = w2 * 32 + __ffs(mm) - 1; break; }
          }
          if (a < 0) continue;               // can't happen (deg <= 96); repair
          if (be < 0) {                      // bank saturated: lane-side place
            mL[hl][l][a] = (unsigned char)b;
            freeL[hl][l][a >> 5] &= ~(1u << (a & 31));
            if (a > maxc) maxc = a;
            continue;
          }
          // walk the a/be alternating path from bank b (collect only)
          int n = 0, curN = b, curCol = a, isbank = 1, of = 0;
          for (;;) {
            int nxt = isbank ? (int)mB[hl][curN][curCol]
                             : (int)mL[hl][curN][curCol];
            if (nxt == NONE_) break;         // terminal = (curN, isbank)
            if (n >= 128) { of = 1; break; }
            pB[hl][n] = (short)(isbank ? curN : nxt);
            pL[hl][n] = (short)(isbank ? nxt : curN);
            ++n;
            curN = nxt; isbank ^= 1;
            curCol = (curCol == a) ? be : a;
          }
          if (of) {                          // bail safely: lane-side place
            mL[hl][l][a] = (unsigned char)b;
            freeL[hl][l][a >> 5] &= ~(1u << (a & 31));
            if (a > maxc) maxc = a;
            continue;
          }
          // flip path: clear pass then set pass (edge i: old (i&1?be:a))
          for (int i = 0; i < n; ++i) {
            int oc = (i & 1) ? be : a;
            mB[hl][pB[hl][i]][oc] = NONE_;
            mL[hl][pL[hl][i]][oc] = NONE_;
          }
          for (int i = 0; i < n; ++i) {
            int nc = (i & 1) ? a : be;
            mB[hl][pB[hl][i]][nc] = (unsigned char)pL[hl][i];
            mL[hl][pL[hl][i]][nc] = (unsigned char)pB[hl][i];
          }
          // endpoint free-mask flips (internals unchanged)
          freeB[hl][b][a >> 5]  ^= (1u << (a & 31));
          freeB[hl][b][be >> 5] ^= (1u << (be & 31));
          if (isbank) {
            freeB[hl][curN][a >> 5]  ^= (1u << (a & 31));
            freeB[hl][curN][be >> 5] ^= (1u << (be & 31));
          } else {
            freeL[hl][curN][a >> 5]  ^= (1u << (a & 31));
            freeL[hl][curN][be >> 5] ^= (1u << (be & 31));
          }
          // now color a is free at both l and b
          mL[hl][l][a] = (unsigned char)b;
          mB[hl][b][a] = (unsigned char)l;
          freeL[hl][l][a >> 5] &= ~(1u << (a & 31));
          freeB[hl][b][a >> 5] &= ~(1u << (a & 31));
          if (a > maxc) maxc = a;
        }
      }
    }
    atomicMax(&cwsh, maxc + 1);
  }
  __syncthreads();

  // repair pass (validity guarantee): per lane, ensure per-bank slot count
  // matches the row's multiplicity; append any deficit at free colors.
  for (int b = 0; b < 32; ++b) {
    int need = __popc((unsigned)occ[lane][b]);
    int have = 0;
    for (int c = 0; c < PAD; ++c) have += (mL[hl][li][c] == b);
    while (have < need) {
      for (int c = 0; c < PAD; ++c)
        if (mL[hl][li][c] == NONE_) {
          mL[hl][li][c] = (unsigned char)b;
          atomicMax(&cwsh, c + 1);
          break;
        }
      ++have;
    }
  }
  __syncthreads();
  if (lane == 0) cntw[g] = cwsh;

  // write phase: slot c of lane -> consume lowest remaining column of the
  // matched bank. Empty slots get val 0 / off 0 (harmless broadcast).
  for (int c = 0; c < PAD; ++c) {
    int b = mL[hl][li][c];
    float v = 0.f; unsigned col = 0u;
    if (b != NONE_) {
      unsigned m16 = (unsigned)occ[lane][b];
      int m = __ffs(m16) - 1;
      occ[lane][b] = (unsigned short)(m16 & (m16 - 1u));
      col = (unsigned)(b + 32 * m);
      v = wrow[col];
    }
    vals[c * NH + p] = v;
    offs[c * NH + p] = col;
  }
}

// ---------------------------------------------------------------------------
// DPP wave-64 sum reduction on the VALU pipe; lane 63 ends with the full sum.
// ---------------------------------------------------------------------------
template <int CTRL, int RM>
__device__ __forceinline__ float dppadd(float v) {
  int t = __builtin_amdgcn_update_dpp(0, __float_as_int(v), CTRL, RM, 0xF, true);
  return v + __int_as_float(t);
}
__device__ __forceinline__ float wave_sum_lane63(float v) {
  v = dppadd<0xB1,  0xF>(v);
  v = dppadd<0x4E,  0xF>(v);
  v = dppadd<0x141, 0xF>(v);
  v = dppadd<0x140, 0xF>(v);
  v = dppadd<0x142, 0xA>(v);
  v = dppadd<0x143, 0xC>(v);
  return v;
}

// fast tanh: (t-1)/(t+1), t = exp(2x), clamp |x|<=9.
__device__ __forceinline__ float ftanh(float x) {
  float xc = fminf(9.0f, fmaxf(-9.0f, x));
  float t  = __expf(2.0f * xc);
  return (t - 1.0f) * __builtin_amdgcn_rcpf(t + 1.0f);
}

// ---------------------------------------------------------------------------
// Main: one block per batch, 512 threads, 2048 sequential steps (x2 unroll).
// (Round-7 kernel, verbatim.)
// ---------------------------------------------------------------------------
#define GA(T_RD, E) (*(const float*)((const char*)(T_RD) + cidx[E]))

#define ESN_STEP(T_RD, T_WR, RWR, SIDX)                                      \
  {                                                                          \
    float d0 = 0.f, d1 = 0.f, d2 = 0.f, d3 = 0.f;                            \
    _Pragma("unroll")                                                        \
    for (int e = 0; e < PAD; e += 8) {                                       \
      if (e < cw) {                                                          \
        d0 = fmaf(wval[e + 0], GA(T_RD, e + 0), d0);                         \
        d1 = fmaf(wval[e + 1], GA(T_RD, e + 1), d1);                         \
        d2 = fmaf(wval[e + 2], GA(T_RD, e + 2), d2);                         \
        d3 = fmaf(wval[e + 3], GA(T_RD, e + 3), d3);                         \
        d0 = fmaf(wval[e + 4], GA(T_RD, e + 4), d0);                         \
        d1 = fmaf(wval[e + 5], GA(T_RD, e + 5), d1);                         \
        d2 = fmaf(wval[e + 6], GA(T_RD, e + 6), d2);                         \
        d3 = fmaf(wval[e + 7], GA(T_RD, e + 7), d3);                         \
      }                                                                      \
    }                                                                        \
    float dot  = (d0 + d1) + (d2 + d3);                                      \
    float xp   = x_lds[SIDX] * w_ih;                                         \
    float dhdt = ((dot - h) + xp) + z_prev * w_zh;                           \
    float hn   = h + 0.1f * dhdt;                                            \
    float thn  = ftanh(hn);                                                  \
    T_WR[row] = thn;                                                         \
    oh[(SIDX) * NH + row] = hn;                                              \
    float pzs = wave_sum_lane63(thn * w_hz);                                 \
    if (lane == 63) red[RWR][wid] = pzs;                                     \
    asm volatile("s_waitcnt lgkmcnt(0)\n\ts_barrier" ::: "memory");          \
    float4 r0 = *(const float4*)&red[RWR][0];                                \
    float4 r1 = *(const float4*)&red[RWR][4];                                \
    float z = ((r0.x + r0.y) + (r0.z + r0.w)) + ((r1.x + r1.y) + (r1.z + r1.w)); \
    if (p == 0) oz[SIDX] = z;                                                \
    z_prev = z; h = hn;                                                      \
  }

__global__ __launch_bounds__(512, 2) void esn_steps(
    const float* __restrict__ x,   const float* __restrict__ h0,
    const float* __restrict__ Wih, const float* __restrict__ Whz,
    const float* __restrict__ Wzh, const float* __restrict__ vals,
    const unsigned* __restrict__ offs, const int* __restrict__ perm,
    const int* __restrict__ cntw, float* __restrict__ out) {
  __shared__ float t_lds[2][NH];              // tanh(h), double-buffered
  __shared__ float x_lds[TT];                 // this batch's input row
  __shared__ __align__(16) float red[2][8];   // cross-wave partials for z

  const int p    = threadIdx.x;               // sorted position owned
  const int b    = blockIdx.x;
  const int lane = p & 63;
  const int wid  = p >> 6;
  const int row  = perm[p];                   // actual hidden unit

  float* t0 = t_lds[0];
  float* t1 = t_lds[1];

  for (int i = p; i < TT; i += NH) x_lds[i] = x[(size_t)b * TT + i];

  int cw = __builtin_amdgcn_readfirstlane((cntw[wid] + 7) & ~7);

  float    wval[PAD];
  unsigned cidx[PAD];
  #pragma unroll
  for (int e = 0; e < PAD; ++e) {
    wval[e] = vals[e * NH + p];
    cidx[e] = offs[e * NH + p] * 4u;
  }
  #pragma unroll
  for (int e = 0; e < PIN; ++e)
    asm volatile("" : "+v"(wval[e]), "+v"(cidx[e]));

  const float w_ih = Wih[row];
  const float w_hz = Whz[row];
  const float w_zh = Wzh[row];
  float h = h0[(size_t)b * NH + row];

  float* oz = out + (size_t)b * TT;                        // z region [B,T,1]
  float* oh = out + (size_t)BB * TT + (size_t)b * TT * NH; // h region [B,T,NH]

  float th0 = ftanh(h);
  t0[row] = th0;
  float pz = wave_sum_lane63(th0 * w_hz);
  if (lane == 63) red[0][wid] = pz;
  __syncthreads();
  float4 i0 = *(const float4*)&red[0][0];
  float4 i1 = *(const float4*)&red[0][4];
  float z_prev = ((i0.x + i0.y) + (i0.z + i0.w)) + ((i1.x + i1.y) + (i1.z + i1.w));

  for (int s = 0; s < TT; s += 2) {
    ESN_STEP(t0, t1, 1, s);
    ESN_STEP(t1, t0, 0, s + 1);
  }
}

// ---------------------------------------------------------------------------
extern "C" void kernel_launch(void* const* d_in, const int* in_sizes, int n_in,
                              void* d_out, int out_size, void* d_ws,
                              size_t ws_size, hipStream_t stream) {
  const float* x   = (const float*)d_in[0];
  const float* h0  = (const float*)d_in[1];
  const float* Wih = (const float*)d_in[2];
  const float* Whh = (const float*)d_in[3];
  const float* Whz = (const float*)d_in[4];
  const float* Wzh = (const float*)d_in[5];
  float* out = (float*)d_out;

  float*    vals = (float*)d_ws;                     // PAD*NH f32 = 192 KB
  unsigned* offs = (unsigned*)(vals + PAD * NH);     // PAD*NH u32 = 192 KB
  int*      nnz  = (int*)(offs + PAD * NH);          // NH
  int*      perm = nnz + NH;                         // NH
  int*      cntw = perm + NH;                        // 8

  hipLaunchKernelGGL(count_nnz, dim3(NH / 8), dim3(512), 0, stream, Whh, nnz);
  hipLaunchKernelGGL(sort_rows, dim3(1), dim3(512), 0, stream, nnz, perm);
  hipLaunchKernelGGL(build_color, dim3(8), dim3(64), 0, stream,
                     Whh, perm, vals, offs, cntw);
  hipLaunchKernelGGL(esn_steps, dim3(BB), dim3(512), 0, stream,
                     x, h0, Wih, Whz, Wzh, vals, offs, perm, cntw, out);
}